// Round 10
// baseline (131.777 us; speedup 1.0000x reference)
//
#include <hip/hip_runtime.h>
#include <hip/hip_bf16.h>

#define NPTS   131072
#define NNODES 2048
#define KSEL   32

// ---- knn decomposition ----
#define TKNN   256                 // threads per knn block
#define PPT    4                   // points per thread = 2 packed f32x2 chains
#define PPG_K  (TKNN * PPT)        // 1024 points per knn group
#define NGRP_K (NPTS / PPG_K)      // 128 knn groups
#define NCHUNK 16                  // node chunks (block-uniform -> s_load)
#define CHN    (NNODES / NCHUNK)   // 128 nodes per chunk

// ---- grouping/scatter decomposition ----
#define GSZ    512                 // points per stability group
#define NG     (NPTS / GSZ)        // 256 groups

typedef unsigned int uint;
typedef unsigned short u16;
typedef unsigned long long u64;
typedef float f2 __attribute__((ext_vector_type(2)));

// node stored pre-splatted: {x,x},{y,y},{z,z},{nn,nn} -> s_load_dwordx8 -> 4 SGPR pairs
struct node8 { f2 x, y, z, w; };

// order-preserving fp32 -> u32 (handles tiny-negative cancellation results)
__device__ __forceinline__ uint f2ord(float d) {
    uint b = __float_as_uint(d);
    return (b & 0x80000000u) ? ~b : (b | 0x80000000u);
}
__device__ __forceinline__ float ord2f(uint t) {
    uint b = (t & 0x80000000u) ? (t ^ 0x80000000u) : ~t;
    return __uint_as_float(b);
}

// --- K0: init knnres to max keys; first 2048 threads also pack splatted nodes ---
__global__ __launch_bounds__(256) void prep_init(const float* __restrict__ nodes,
                                                 node8* __restrict__ n8,
                                                 u64* __restrict__ knnres) {
    int i = blockIdx.x * 256 + threadIdx.x;
    knnres[i] = ~0ull;
    if (i < NNODES) {
        float x = nodes[3 * i], y = nodes[3 * i + 1], z = nodes[3 * i + 2];
        // |n|^2 with numpy's mul-then-add rounding
        float nn = __fadd_rn(__fadd_rn(__fmul_rn(x, x), __fmul_rn(y, y)), __fmul_rn(z, z));
        node8 v;
        v.x = (f2){x, x}; v.y = (f2){y, y}; v.z = (f2){z, z}; v.w = (f2){nn, nn};
        n8[i] = v;
    }
}

// --- K1: partial 1-NN, 4 pts/thread; whole node loop in ONE asm block ---
// Per half: m = nx*x; r = fma(ny,y,m); r = fma(nz,z,r); d = (pp + r) + nn
// == reference (pp - 2*dot) + nn bit-exactly (n* = -2*p* exact; v_pk_* IEEE-rn per
// half). Strict < ascending jj = first-occurrence argmin; cross-chunk merge via
// u64 atomicMin on (ord(d2) << 32 | node) keys.
__global__ __launch_bounds__(256) void knn_part(const float* __restrict__ pts,
                                                const node8* __restrict__ n8,
                                                u64* __restrict__ knnres) {
    int bid = blockIdx.x;
    int c   = bid & (NCHUNK - 1);            // block-uniform chunk
    int g   = bid >> 4;                      // knn point group
    int t   = threadIdx.x;

    // load 4 points, pack into 2 chains: chain q holds points (2q, 2q+1) in (lo,hi)
    f2 pp2[2], nx2[2], ny2[2], nz2[2];
    #pragma unroll
    for (int q = 0; q < 2; ++q) {
        #pragma unroll
        for (int h = 0; h < 2; ++h) {
            int pid = g * PPG_K + (2 * q + h) * TKNN + t;
            float p0 = pts[3 * pid], p1 = pts[3 * pid + 1], p2 = pts[3 * pid + 2];
            float pp = __fadd_rn(__fadd_rn(__fmul_rn(p0, p0), __fmul_rn(p1, p1)),
                                 __fmul_rn(p2, p2));
            pp2[q][h] = pp;
            nx2[q][h] = __fmul_rn(-2.0f, p0);   // exact
            ny2[q][h] = __fmul_rn(-2.0f, p1);
            nz2[q][h] = __fmul_rn(-2.0f, p2);
        }
    }

    const node8* np = n8 + c * CHN;          // block-uniform base
    float b0 = 3.4e38f, b1 = 3.4e38f, b2 = 3.4e38f, b3 = 3.4e38f;
    uint  i0 = 0, i1 = 0, i2 = 0, i3 = 0;
    uint  vj = 0;

    // 64 iterations x 2 nodes = 128 nodes. Explicit regs: s[12:13] base walk,
    // s[16:23]/s[24:31] node double-slot, v0-v3 d2 temps, s8 counter.
    asm volatile(
        "s_mov_b64 s[12:13], %[np]\n\t"
        "s_mov_b32 s8, 0\n\t"
        "1:\n\t"
        "s_load_dwordx8 s[16:23], s[12:13], 0x0\n\t"
        "s_load_dwordx8 s[24:31], s[12:13], 0x20\n\t"
        "s_waitcnt lgkmcnt(0)\n\t"
        // ---- node A: chain0 -> v[0:1], chain1 -> v[2:3]
        "v_pk_mul_f32 v[0:1], %[nx0], s[16:17]\n\t"
        "v_pk_fma_f32 v[0:1], %[ny0], s[18:19], v[0:1]\n\t"
        "v_pk_fma_f32 v[0:1], %[nz0], s[20:21], v[0:1]\n\t"
        "v_pk_add_f32 v[0:1], %[pp0], v[0:1]\n\t"
        "v_pk_add_f32 v[0:1], v[0:1], s[22:23]\n\t"
        "v_pk_mul_f32 v[2:3], %[nx1], s[16:17]\n\t"
        "v_pk_fma_f32 v[2:3], %[ny1], s[18:19], v[2:3]\n\t"
        "v_pk_fma_f32 v[2:3], %[nz1], s[20:21], v[2:3]\n\t"
        "v_pk_add_f32 v[2:3], %[pp1], v[2:3]\n\t"
        "v_pk_add_f32 v[2:3], v[2:3], s[22:23]\n\t"
        "v_cmp_lt_f32 vcc, v0, %[b0]\n\t"
        "v_cndmask_b32 %[b0], %[b0], v0, vcc\n\t"
        "v_cndmask_b32 %[i0], %[i0], %[vj], vcc\n\t"
        "v_cmp_lt_f32 vcc, v1, %[b1]\n\t"
        "v_cndmask_b32 %[b1], %[b1], v1, vcc\n\t"
        "v_cndmask_b32 %[i1], %[i1], %[vj], vcc\n\t"
        "v_cmp_lt_f32 vcc, v2, %[b2]\n\t"
        "v_cndmask_b32 %[b2], %[b2], v2, vcc\n\t"
        "v_cndmask_b32 %[i2], %[i2], %[vj], vcc\n\t"
        "v_cmp_lt_f32 vcc, v3, %[b3]\n\t"
        "v_cndmask_b32 %[b3], %[b3], v3, vcc\n\t"
        "v_cndmask_b32 %[i3], %[i3], %[vj], vcc\n\t"
        "v_add_u32 %[vj], 1, %[vj]\n\t"
        // ---- node B: same with s[24:31]
        "v_pk_mul_f32 v[0:1], %[nx0], s[24:25]\n\t"
        "v_pk_fma_f32 v[0:1], %[ny0], s[26:27], v[0:1]\n\t"
        "v_pk_fma_f32 v[0:1], %[nz0], s[28:29], v[0:1]\n\t"
        "v_pk_add_f32 v[0:1], %[pp0], v[0:1]\n\t"
        "v_pk_add_f32 v[0:1], v[0:1], s[30:31]\n\t"
        "v_pk_mul_f32 v[2:3], %[nx1], s[24:25]\n\t"
        "v_pk_fma_f32 v[2:3], %[ny1], s[26:27], v[2:3]\n\t"
        "v_pk_fma_f32 v[2:3], %[nz1], s[28:29], v[2:3]\n\t"
        "v_pk_add_f32 v[2:3], %[pp1], v[2:3]\n\t"
        "v_pk_add_f32 v[2:3], v[2:3], s[30:31]\n\t"
        "v_cmp_lt_f32 vcc, v0, %[b0]\n\t"
        "v_cndmask_b32 %[b0], %[b0], v0, vcc\n\t"
        "v_cndmask_b32 %[i0], %[i0], %[vj], vcc\n\t"
        "v_cmp_lt_f32 vcc, v1, %[b1]\n\t"
        "v_cndmask_b32 %[b1], %[b1], v1, vcc\n\t"
        "v_cndmask_b32 %[i1], %[i1], %[vj], vcc\n\t"
        "v_cmp_lt_f32 vcc, v2, %[b2]\n\t"
        "v_cndmask_b32 %[b2], %[b2], v2, vcc\n\t"
        "v_cndmask_b32 %[i2], %[i2], %[vj], vcc\n\t"
        "v_cmp_lt_f32 vcc, v3, %[b3]\n\t"
        "v_cndmask_b32 %[b3], %[b3], v3, vcc\n\t"
        "v_cndmask_b32 %[i3], %[i3], %[vj], vcc\n\t"
        "v_add_u32 %[vj], 1, %[vj]\n\t"
        // ---- advance and loop
        "s_add_u32 s12, s12, 64\n\t"
        "s_addc_u32 s13, s13, 0\n\t"
        "s_add_u32 s8, s8, 1\n\t"
        "s_cmp_lt_u32 s8, 64\n\t"
        "s_cbranch_scc1 1b\n\t"
        : [b0]"+v"(b0), [b1]"+v"(b1), [b2]"+v"(b2), [b3]"+v"(b3),
          [i0]"+v"(i0), [i1]"+v"(i1), [i2]"+v"(i2), [i3]"+v"(i3),
          [vj]"+v"(vj)
        : [np]"s"(np),
          [nx0]"v"(nx2[0]), [ny0]"v"(ny2[0]), [nz0]"v"(nz2[0]), [pp0]"v"(pp2[0]),
          [nx1]"v"(nx2[1]), [ny1]"v"(ny2[1]), [nz1]"v"(nz2[1]), [pp1]"v"(pp2[1])
        : "s8", "s12", "s13", "s16", "s17", "s18", "s19", "s20", "s21", "s22", "s23",
          "s24", "s25", "s26", "s27", "s28", "s29", "s30", "s31",
          "v0", "v1", "v2", "v3", "vcc", "scc", "memory");

    float best[PPT] = {b0, b1, b2, b3};
    uint  bi[PPT]   = {i0, i1, i2, i3};
    #pragma unroll
    for (int h = 0; h < PPT; ++h) {
        int pid = g * PPG_K + h * TKNN + t;
        u64 key = ((u64)f2ord(best[h]) << 32) | (uint)(c * CHN + bi[h]);
        atomicMin(&knnres[pid], key);        // min key == (min d2, then min node idx)
    }
}

// --- K2: decode winners, write d2/id/pcd, per-group u16 histogram, zero patch ---
__global__ __launch_bounds__(256) void merge_hist(const u64* __restrict__ knnres,
                                                  float* __restrict__ out_d2,
                                                  float* __restrict__ out_id,
                                                  int* __restrict__ pcd,
                                                  u16* __restrict__ hist16,
                                                  float* __restrict__ patch) {
    __shared__ uint lh[NNODES];
    int g = blockIdx.x, t = threadIdx.x;
    patch[(size_t)g * 256 + t] = 0.0f;       // 256x256 = full 65536-float patch zeroed
    for (int i = t; i < NNODES; i += 256) lh[i] = 0;
    __syncthreads();

    #pragma unroll
    for (int q = 0; q < GSZ / 256; ++q) {
        int pid = g * GSZ + q * 256 + t;
        u64 key = knnres[pid];
        uint bi = (uint)key;                 // low 32: node index
        float d = ord2f((uint)(key >> 32));  // exact d2 decode
        atomicAdd(&lh[bi], 1u);
        out_d2[pid] = d;
        out_id[pid] = (float)bi;             // exact: bi < 2^24
        pcd[pid]    = (int)bi;
    }
    __syncthreads();
    for (int i = t; i < NNODES; i += 256)
        hist16[(size_t)g * NNODES + i] = (u16)lh[i];   // contiguous stores
}

// --- K3: per-node exclusive prefix across the 256 groups; offs in [node][group] ---
__global__ __launch_bounds__(256) void scan_offs(const u16* __restrict__ hist16,
                                                 uint* __restrict__ offs) {
    int t = threadIdx.x, lane = t & 63, wv = t >> 6;
    int node = blockIdx.x * 4 + wv;

    uint v0 = hist16[(size_t)(4 * lane + 0) * NNODES + node];
    uint v1 = hist16[(size_t)(4 * lane + 1) * NNODES + node];
    uint v2 = hist16[(size_t)(4 * lane + 2) * NNODES + node];
    uint v3 = hist16[(size_t)(4 * lane + 3) * NNODES + node];
    uint s = v0 + v1 + v2 + v3;
    uint a = s;
    #pragma unroll
    for (int d = 1; d < 64; d <<= 1) {
        uint y = __shfl_up(a, d, 64);
        if (lane >= d) a += y;
    }
    uint base = a - s;                        // exclusive across lanes
    uint4 o = make_uint4(base, base + v0, base + v0 + v1, base + v0 + v1 + v2);
    *(uint4*)(offs + (size_t)node * NG + 4 * lane) = o;   // contiguous 16B store
}

// --- K4: stable scatter of first-32 point indices per node ---
__global__ __launch_bounds__(256) void scatter_patch(const int* __restrict__ pcd,
                                                     const uint* __restrict__ offs,
                                                     float* __restrict__ patch) {
    __shared__ int ids[GSZ];
    int g = blockIdx.x, t = threadIdx.x;
    ids[t]       = pcd[g * GSZ + t];
    ids[256 + t] = pcd[g * GSZ + 256 + t];
    __syncthreads();

    int i0 = t, i1 = 256 + t;
    int my0 = ids[i0], my1 = ids[i1];
    int r0 = 0, r1 = 0;
    #pragma unroll 8
    for (int j = 0; j < GSZ; ++j) {
        int id = ids[j];                      // broadcast LDS read, conflict-free
        r0 += (j < i0 && id == my0) ? 1 : 0;
        r1 += (j < i1 && id == my1) ? 1 : 0;
    }
    uint rk0 = offs[(size_t)my0 * NG + g] + (uint)r0;
    uint rk1 = offs[(size_t)my1 * NG + g] + (uint)r1;
    if (rk0 < KSEL) patch[(size_t)my0 * KSEL + rk0] = (float)(g * GSZ + i0);
    if (rk1 < KSEL) patch[(size_t)my1 * KSEL + rk1] = (float)(g * GSZ + i1);
}

extern "C" void kernel_launch(void* const* d_in, const int* in_sizes, int n_in,
                              void* d_out, int out_size, void* d_ws, size_t ws_size,
                              hipStream_t stream) {
    const float* pts   = (const float*)d_in[0];
    const float* nodes = (const float*)d_in[1];

    float* out       = (float*)d_out;
    float* out_d2    = out;                  // 131072 floats
    float* out_id    = out + NPTS;           // 131072 floats
    float* out_patch = out + 2 * NPTS;       // 65536 floats

    // workspace: ~4.6 MB
    char* ws = (char*)d_ws;
    u64*   knnres = (u64*) ws;                               // 1 MB   (131072 x u64)
    u16*   hist16 = (u16*) (ws + (1 << 20));                 // 1 MB   (256 x 2048 u16)
    uint*  offs   = (uint*) (ws + (2 << 20));                // 2 MB   (2048 x 256 u32)
    int*   pcd    = (int*)  (ws + (4 << 20));                // 512 KB
    node8* n8     = (node8*)(ws + (4 << 20) + (512 << 10));  // 64 KB

    prep_init<<<NPTS / 256, 256, 0, stream>>>(nodes, n8, knnres);
    knn_part<<<NGRP_K * NCHUNK, TKNN, 0, stream>>>(pts, n8, knnres);
    merge_hist<<<NG, 256, 0, stream>>>(knnres, out_d2, out_id, pcd, hist16, out_patch);
    scan_offs<<<NNODES / 4, 256, 0, stream>>>(hist16, offs);
    scatter_patch<<<NG, 256, 0, stream>>>(pcd, offs, out_patch);
}